// Round 6
// baseline (129.355 us; speedup 1.0000x reference)
//
#include <hip/hip_runtime.h>
#include <hip/hip_bf16.h>
#include <hip/hip_fp8.h>

// SimCLR NT-Xent loss on MI355X.
// loss = -(1/2B) sum_t [ 10*G[t,j0(t)] - (10 + log sum_{j!=t} exp(10*G[t,j]-10)) ]
// where G = M M^T, M = l2norm rows of [z_i; z_j], j0 = (t%B==0) ? 1 : 0.
// Round 11: OCCUPANCY + zero-barrier + zero-atomic, simultaneously.
// Cross-round evidence: only the 4-blocks/CU variant (R2) beat 44 us; the
// zero-barrier/zero-atomic rewrites (R4/R5) ran at 2 blocks/CU (64 KB LDS)
// and stayed latency-bound at 45-52 us with every pipe <25%. This round:
// 256x64 tiles -> B-panel LDS = 32 KB -> 4 blocks/CU (4 waves/SIMD), keep
// streaming loop (1 barrier/block), plain-store slice partials, MX fp8.
// Also halves ds_read:MFMA ratio to 1:1 (each B fragment feeds 2 MFMAs).

#define BB 4096      // batch B
#define DD 512       // feature dim (bytes per row in fp8)
#define NN 8192      // 2B rows of G
#define TM 256       // tile rows (4 waves x 64)
#define TN 64        // tile cols
#define NRP 32       // row panels (NN/TM)
#define NCT 128      // col tiles  (NN/TN)
#define NBLK 2112    // sum_{bx<32} (128-4bx)
#define NSLICE 256   // 128 row-path (slice=cy) + 128 col-path (128+bx*4+wave)

typedef __attribute__((ext_vector_type(4)))  float f32x4;
typedef __attribute__((ext_vector_type(16))) float f32x16;
typedef __attribute__((ext_vector_type(4)))  int   i32x4;
typedef __attribute__((ext_vector_type(8)))  int   i32x8;

#define AS1 __attribute__((address_space(1)))
#define AS3 __attribute__((address_space(3)))
static __device__ __forceinline__ void gload_lds16(const void* g, void* l) {
    __builtin_amdgcn_global_load_lds((const AS1 void*)g, (AS3 void*)l, 16, 0, 0);
}

// ---------------- kernel 1: L2-normalize rows -> fp8; zero rpart/wacc ------
// One wave per row: 64 lanes x 8 f32, shuffle reduce, no LDS/barrier.
// Also zeroes the 8 MB rpart (one f32x4 store per thread, exact cover).
__global__ __launch_bounds__(256)
void normalize_kernel(const float* __restrict__ zi, const float* __restrict__ zj,
                      unsigned char* __restrict__ M, float* __restrict__ rpart,
                      float* __restrict__ wacc) {
    const int gt = blockIdx.x * 256 + threadIdx.x;   // 524288 threads
    ((f32x4*)rpart)[gt] = (f32x4){0.f, 0.f, 0.f, 0.f};   // 8 MB = NSLICE*NN*4B
    if (gt == 0) wacc[0] = 0.f;

    const int wave = threadIdx.x >> 6;
    const int lane = threadIdx.x & 63;
    const int row  = blockIdx.x * 4 + wave;      // 2048 blocks * 4 rows
    const float* src = (row < BB) ? (zi + (size_t)row * DD)
                                  : (zj + (size_t)(row - BB) * DD);
    float4 v0 = ((const float4*)src)[lane * 2 + 0];
    float4 v1 = ((const float4*)src)[lane * 2 + 1];
    float ss = v0.x*v0.x + v0.y*v0.y + v0.z*v0.z + v0.w*v0.w
             + v1.x*v1.x + v1.y*v1.y + v1.z*v1.z + v1.w*v1.w;
    #pragma unroll
    for (int off = 1; off <= 32; off <<= 1) ss += __shfl_xor(ss, off);
    const float inv = rsqrtf(ss);
    const float vals[8] = {v0.x*inv, v0.y*inv, v0.z*inv, v0.w*inv,
                           v1.x*inv, v1.y*inv, v1.z*inv, v1.w*inv};
    union { long u; unsigned char b[8]; } pk;
    #pragma unroll
    for (int j = 0; j < 8; ++j)
        pk.b[j] = __hip_cvt_float_to_fp8(vals[j], __HIP_SATFINITE, __HIP_E4M3);
    ((long*)(M + (size_t)row * DD))[lane] = pk.u;
}

// ---------------- kernel 2: Gram tile + exp partial sums -------------------
// 2112 blocks; tile (bx, cy): rows [bx*256, +256), cols [cy*64, +64),
// kept iff cy >= 4*bx. inDiag tiles (cy-4bx < 4) lie inside the diagonal
// 256-superblock: mask grow==gcol, skip col path (the 4 sub-tiles cover
// both (r,c) and (c,r) directly). Wave w owns rows [w*64, +64): acc[2][2]
// of 32x32, A from global (per-lane, L2-hot), B panel in LDS (32 KB,
// XOR-swizzled 16B granules, verified conflict-free in R4/R5).
__global__ __launch_bounds__(256, 4)
void gram_lse_kernel(const unsigned char* __restrict__ Mg,
                     float* __restrict__ rpart, float* __restrict__ targets) {
    __shared__ __align__(16) char Bs[TN * DD];   // 32 KB

    // XCD-banded order: dispatch d -> band d%8 (one XCD), 264 tiles/band.
    const int d = blockIdx.x;
    const int p = (d & 7) * (NBLK / 8) + (d >> 3);
    // inverse of C(b) = 130b - 2b^2 (tiles before row-panel b)
    int bx = (int)((130.f - sqrtf(16900.f - 8.f * (float)p)) * 0.25f);
    while (130 * (bx + 1) - 2 * (bx + 1) * (bx + 1) <= p) ++bx;
    while (130 * bx - 2 * bx * bx > p) --bx;
    const int cy = 4 * bx + (p - (130 * bx - 2 * bx * bx));
    const bool inDiag = (cy - 4 * bx) < 4;

    const int rowBase = bx * TM;
    const int colBase = cy * TN;
    const int tid  = threadIdx.x;
    const int wave = tid >> 6;
    const int lane = tid & 63;
    const int l31 = lane & 31;
    const int h0  = lane >> 5;          // k-half: 0 -> k[0:32), 1 -> k[32:64) per chunk

    // ---- stage B panel (64 rows x 512 B): 8 issues, 16 B per thread ----
    // dest granule q = i*256+tid -> row = q>>5 = i*8+(tid>>5), pos = tid&31;
    // source granule sg = pos ^ (row&31). Wave dest is lane-linear.
    #pragma unroll
    for (int i = 0; i < 8; ++i) {
        const int row = i * 8 + (tid >> 5);
        const int sgr = (tid & 31) ^ (row & 31);
        gload_lds16(Mg + (size_t)(colBase + row) * DD + sgr * 16,
                    Bs + ((size_t)i * 256 + tid) * 16);
    }

    // A: lane holds rows rowBase + wave*64 + l31 (+32 for mi=1), k-half h0.
    const unsigned char* A0 =
        Mg + (size_t)(rowBase + wave * 64 + l31) * DD + h0 * 32;

    __syncthreads();   // the ONLY barrier: B panel resident

    // ---- barrier-free main loop: 8 chunks x (4 ds_read_b128 + 4 MFMA) ----
    f32x16 acc[2][2] = {};
    const char* Brow0 = Bs + l31 * DD;
    #pragma unroll
    for (int t = 0; t < 8; ++t) {
        i32x4 a0l = *(const i32x4*)(A0 + t * 64);
        i32x4 a0h = *(const i32x4*)(A0 + t * 64 + 16);
        i32x4 a1l = *(const i32x4*)(A0 + 32 * DD + t * 64);
        i32x4 a1h = *(const i32x4*)(A0 + 32 * DD + t * 64 + 16);
        const i32x8 a0 = __builtin_shufflevector(a0l, a0h, 0, 1, 2, 3, 4, 5, 6, 7);
        const i32x8 a1 = __builtin_shufflevector(a1l, a1h, 0, 1, 2, 3, 4, 5, 6, 7);
        // B fragment: granules g0 = t*4 + 2h0, g0+1; stored at pos g ^ l31.
        const int p0 = ((t * 4 + h0 * 2) ^ l31) * 16;
        #pragma unroll
        for (int ni = 0; ni < 2; ++ni) {
            const char* rb = Brow0 + ni * 32 * DD;
            i32x4 lo = *(const i32x4*)(rb + p0);
            i32x4 hi = *(const i32x4*)(rb + (p0 ^ 16));
            i32x8 b = __builtin_shufflevector(lo, hi, 0, 1, 2, 3, 4, 5, 6, 7);
            // Unity e8m0 scales (0x7F = 2^0); cbsz/blgp 0 -> fp8 e4m3.
            acc[0][ni] = __builtin_amdgcn_mfma_scale_f32_32x32x64_f8f6f4(
                a0, b, acc[0][ni], 0, 0, 0, 0x7F7F7F7F, 0, 0x7F7F7F7F);
            acc[1][ni] = __builtin_amdgcn_mfma_scale_f32_32x32x64_f8f6f4(
                a1, b, acc[1][ni], 0, 0, 0, 0x7F7F7F7F, 0, 0x7F7F7F7F);
        }
    }

    // ---- epilogue ----
    // 32x32 C/D layout: col = lane&31, row = (reg&3) + 8*(reg>>2) + 4*(lane>>5)
    // e = exp(10*G - 10) = exp2(G*C - C), C = 10*log2(e).
    const float C10 = 14.42695040888963f;
    float rs[2][16] = {};
    float cs[2] = {0.f, 0.f};
    #pragma unroll
    for (int ni = 0; ni < 2; ++ni) {
        const int gcol = colBase + ni * 32 + l31;
        #pragma unroll
        for (int mi = 0; mi < 2; ++mi) {
            #pragma unroll
            for (int r = 0; r < 16; ++r) {
                const int lrow = (r & 3) + 8 * (r >> 2) + 4 * h0;
                const int grow = rowBase + wave * 64 + mi * 32 + lrow;
                float e = __builtin_amdgcn_exp2f(fmaf(acc[mi][ni][r], C10, -C10));
                if (inDiag && grow == gcol) e = 0.f;   // exclude diagonal
                rs[mi][r] += e;
                cs[ni] += e;
                // targets: rows 0/1 of G give 10*G[t, j0] transposed.
                // Only bx==0, wave 0, mi 0, h0 0, r<2 hits; disjoint cols.
                if (rowBase == 0 && wave == 0 && mi == 0 && grow < 2) {
                    const int j0 = ((gcol & (BB - 1)) == 0) ? 1 : 0;
                    if (grow == j0) targets[gcol] = 10.f * acc[mi][ni][r];
                }
            }
        }
    }
    // Row sums -> slice cy (unique writer per (cy, row)). Butterfly over
    // the 32 col-lanes; h0 halves hold different rows.
    #pragma unroll
    for (int m = 1; m <= 16; m <<= 1)
        #pragma unroll
        for (int mi = 0; mi < 2; ++mi)
            #pragma unroll
            for (int r = 0; r < 16; ++r)
                rs[mi][r] += __shfl_xor(rs[mi][r], m);
    if (l31 == 0) {
        #pragma unroll
        for (int mi = 0; mi < 2; ++mi)
            #pragma unroll
            for (int r = 0; r < 16; ++r)
                rpart[(size_t)cy * NN + rowBase + wave * 64 + mi * 32
                      + (r & 3) + 8 * (r >> 2) + 4 * h0] = rs[mi][r];
    }
    // Col sums -> slice 128 + bx*4 + wave (unique writer per (slice, col));
    // per-wave partial over its 64 rows; reduce_kernel folds the rest.
    if (!inDiag) {
        cs[0] += __shfl_xor(cs[0], 32);
        cs[1] += __shfl_xor(cs[1], 32);
        if (h0 == 0) {
            const size_t sbase = (size_t)(NCT + bx * 4 + wave) * NN + colBase;
            rpart[sbase + l31]      = cs[0];
            rpart[sbase + 32 + l31] = cs[1];
        }
    }
}

// ---------------- kernel 3: fold 256 slices per row + loss term ------------
// 32 blocks x 256 threads, one row each; coalesced slice reads (8 MB).
__global__ __launch_bounds__(256)
void reduce_kernel(const float* __restrict__ rpart,
                   const float* __restrict__ targets, float* __restrict__ wacc) {
    const int i = blockIdx.x * 256 + threadIdx.x;
    float s = 0.f;
    #pragma unroll 8
    for (int sl = 0; sl < NSLICE; ++sl)
        s += rpart[(size_t)sl * NN + i];
    float term = targets[i] - 10.f - __logf(s);
    #pragma unroll
    for (int off = 1; off <= 32; off <<= 1) term += __shfl_xor(term, off);
    __shared__ float red[4];
    if ((threadIdx.x & 63) == 0) red[threadIdx.x >> 6] = term;
    __syncthreads();
    if (threadIdx.x == 0)
        atomicAdd(wacc, red[0] + red[1] + red[2] + red[3]);
}

// ---------------- kernel 4: write scalar output ----------------------------
__global__ void write_kernel(const float* __restrict__ wacc,
                             float* __restrict__ out) {
    out[0] = -wacc[0] / (float)NN;
}

extern "C" void kernel_launch(void* const* d_in, const int* in_sizes, int n_in,
                              void* d_out, int out_size, void* d_ws, size_t ws_size,
                              hipStream_t stream) {
    const float* zi = (const float*)d_in[0];
    const float* zj = (const float*)d_in[1];

    unsigned char* M = (unsigned char*)d_ws;                          // 4 MB fp8
    float* rpart   = (float*)((char*)d_ws + (size_t)NN * DD);         // 8 MB
    float* targets = rpart + (size_t)NSLICE * NN;                     // 32 KB
    float* wacc    = targets + NN;                                    // 4 B
    float* out = (float*)d_out;

    normalize_kernel<<<NN / 4, 256, 0, stream>>>(zi, zj, M, rpart, wacc);
    gram_lse_kernel<<<NBLK, 256, 0, stream>>>(M, rpart, targets);
    reduce_kernel<<<NN / 256, 256, 0, stream>>>(rpart, targets, wacc);
    write_kernel<<<1, 1, 0, stream>>>(wacc, out);
}

// Round 7
// 121.254 us; speedup vs baseline: 1.0668x; 1.0668x over previous
//
#include <hip/hip_runtime.h>
#include <hip/hip_bf16.h>
#include <hip/hip_fp8.h>

// SimCLR NT-Xent loss on MI355X.
// loss = -(1/2B) sum_t [ 10*G[t,j0(t)] - (10 + log sum_{j!=t} exp(10*G[t,j]-10)) ]
// where G = M M^T, M = l2norm rows of [z_i; z_j], j0 = (t%B==0) ? 1 : 0.
// Round 12: A pinned in VGPRs (asm-pinned so the compiler CANNOT sink the
// loads back into the loop, which it did in R4/R6 -> VGPR_Count 64/88 and
// per-chunk L2 round-trips), B panel in 32 KB LDS -> 4 blocks/CU, zero
// barriers in the main loop, zero atomics, NO rpart zeroing (reducer uses
// exact closed-form validity bounds). Wave = 32x64 out: acc 32 + A 64 +
// transients ~ 120 VGPR <= 128 cap at launch_bounds(256,4).

#define BB 4096      // batch B
#define DD 512       // feature dim (bytes per row in fp8)
#define NN 8192      // 2B rows of G
#define TM 128       // tile rows (4 waves x 32)
#define TN 64        // tile cols
#define NBLK 4160    // sum_{bx<64} (128-2bx) = 64*65
#define NSLICE 192   // 128 row-path (slice=cy) + 64 col-path (slice=128+bx)

typedef __attribute__((ext_vector_type(4)))  float f32x4;
typedef __attribute__((ext_vector_type(16))) float f32x16;
typedef __attribute__((ext_vector_type(4)))  int   i32x4;
typedef __attribute__((ext_vector_type(8)))  int   i32x8;

#define AS1 __attribute__((address_space(1)))
#define AS3 __attribute__((address_space(3)))
static __device__ __forceinline__ void gload_lds16(const void* g, void* l) {
    __builtin_amdgcn_global_load_lds((const AS1 void*)g, (AS3 void*)l, 16, 0, 0);
}

// ---------------- kernel 1: L2-normalize rows -> fp8; zero wacc ------------
// One wave per row: 64 lanes x 8 f32, shuffle reduce, no LDS/barrier.
__global__ __launch_bounds__(256)
void normalize_kernel(const float* __restrict__ zi, const float* __restrict__ zj,
                      unsigned char* __restrict__ M, float* __restrict__ wacc) {
    if (blockIdx.x == 0 && threadIdx.x == 0) wacc[0] = 0.f;
    const int wave = threadIdx.x >> 6;
    const int lane = threadIdx.x & 63;
    const int row  = blockIdx.x * 4 + wave;      // 2048 blocks * 4 rows
    const float* src = (row < BB) ? (zi + (size_t)row * DD)
                                  : (zj + (size_t)(row - BB) * DD);
    float4 v0 = ((const float4*)src)[lane * 2 + 0];
    float4 v1 = ((const float4*)src)[lane * 2 + 1];
    float ss = v0.x*v0.x + v0.y*v0.y + v0.z*v0.z + v0.w*v0.w
             + v1.x*v1.x + v1.y*v1.y + v1.z*v1.z + v1.w*v1.w;
    #pragma unroll
    for (int off = 1; off <= 32; off <<= 1) ss += __shfl_xor(ss, off);
    const float inv = rsqrtf(ss);
    const float vals[8] = {v0.x*inv, v0.y*inv, v0.z*inv, v0.w*inv,
                           v1.x*inv, v1.y*inv, v1.z*inv, v1.w*inv};
    union { long u; unsigned char b[8]; } pk;
    #pragma unroll
    for (int j = 0; j < 8; ++j)
        pk.b[j] = __hip_cvt_float_to_fp8(vals[j], __HIP_SATFINITE, __HIP_E4M3);
    ((long*)(M + (size_t)row * DD))[lane] = pk.u;
}

// ---------------- kernel 2: Gram tile + exp partial sums -------------------
// 4160 blocks; tile (bx, cy): rows [bx*128, +128), cols [cy*64, +64),
// kept iff cy >= 2*bx. inDiag (cy-2bx < 2): tile lies in the diagonal
// 128x128 superblock -> mask grow==gcol, skip col path (the 2 sub-tiles
// cover both orientations). Wave w owns rows [w*32, +32): acc[2] of 32x32.
// A: 16 x i32x4 per lane, loaded once, ASM-PINNED (cannot be re-sunk).
// B: 64-row panel in LDS (32 KB), XOR-swizzled granules (R6-verified,
// SQ_LDS_BANK_CONFLICT = 0). Main loop: no barriers, no global ops.
__global__ __launch_bounds__(256, 4)
void gram_lse_kernel(const unsigned char* __restrict__ Mg,
                     float* __restrict__ rpart, float* __restrict__ targets) {
    __shared__ __align__(16) char Bs[TN * DD];   // 32 KB

    // XCD-banded order: dispatch d -> band d%8 (one XCD), 520 tiles/band.
    const int d = blockIdx.x;
    const int p = (d & 7) * (NBLK / 8) + (d >> 3);
    // cumulative C(b) = b*(129-b); decode p -> bx = max{b : C(b) <= p}
    int bx = (int)((129.f - sqrtf(16641.f - 4.f * (float)p)) * 0.5f);
    while ((bx + 1) * (129 - (bx + 1)) <= p) ++bx;
    while (bx * (129 - bx) > p) --bx;
    const int rem = p - bx * (129 - bx);
    const int cy = 2 * bx + rem;
    const bool inDiag = rem < 2;

    const int rowBase = bx * TM;
    const int colBase = cy * TN;
    const int tid  = threadIdx.x;
    const int wave = tid >> 6;
    const int lane = tid & 63;
    const int l31 = lane & 31;
    const int h0  = lane >> 5;          // k-half: 0 -> k[0:32), 1 -> k[32:64) per chunk

    // ---- stage B panel (64 rows x 512 B = 32 KB): 8 issues, 16 B/thread ----
    // dest granule q = i*256+tid -> row = i*8+(tid>>5), pos = tid&31;
    // source granule sg = pos ^ (row&31). Wave dest is lane-linear.
    #pragma unroll
    for (int i = 0; i < 8; ++i) {
        const int row = i * 8 + (tid >> 5);
        const int sgr = (tid & 31) ^ (row & 31);
        gload_lds16(Mg + (size_t)(colBase + row) * DD + sgr * 16,
                    Bs + ((size_t)i * 256 + tid) * 16);
    }

    // ---- A into registers, ONCE, pinned ----
    // lane (l31, h0): row rowBase + wave*32 + l31, k-half h0 -> 256 B.
    const unsigned char* A0 =
        Mg + (size_t)(rowBase + wave * 32 + l31) * DD + h0 * 32;
    i32x4 a4[16];
    #pragma unroll
    for (int t = 0; t < 8; ++t) {
        a4[2 * t]     = *(const i32x4*)(A0 + t * 64);
        a4[2 * t + 1] = *(const i32x4*)(A0 + t * 64 + 16);
    }
    #pragma unroll
    for (int q = 0; q < 16; ++q)
        asm volatile("" : "+v"(a4[q]));   // pin: asm output, cannot re-load

    __syncthreads();   // the ONLY barrier before the loop: B panel resident

    // ---- barrier-free main loop: 8 chunks x (4 ds_read_b128 + 2 MFMA) ----
    f32x16 acc[2] = {};
    #pragma unroll
    for (int t = 0; t < 8; ++t) {
        const i32x8 a = __builtin_shufflevector(a4[2 * t], a4[2 * t + 1],
                                                0, 1, 2, 3, 4, 5, 6, 7);
        // B fragment: granules g0 = t*4 + 2h0, g0+1; stored at pos g ^ row&31,
        // row = ni*32 + l31 -> row&31 = l31 (g0 even -> +1 flips bit0).
        const int p0 = ((t * 4 + h0 * 2) ^ l31) * 16;
        #pragma unroll
        for (int ni = 0; ni < 2; ++ni) {
            const char* rb = Bs + (ni * 32 + l31) * DD;
            i32x4 lo = *(const i32x4*)(rb + p0);
            i32x4 hi = *(const i32x4*)(rb + (p0 ^ 16));
            i32x8 b = __builtin_shufflevector(lo, hi, 0, 1, 2, 3, 4, 5, 6, 7);
            // Unity e8m0 scales (0x7F = 2^0); cbsz/blgp 0 -> fp8 e4m3.
            acc[ni] = __builtin_amdgcn_mfma_scale_f32_32x32x64_f8f6f4(
                a, b, acc[ni], 0, 0, 0, 0x7F7F7F7F, 0, 0x7F7F7F7F);
        }
    }

    // ---- epilogue ----
    // 32x32 C/D layout: col = lane&31, row = (reg&3) + 8*(reg>>2) + 4*(lane>>5)
    // e = exp(10*G - 10) = exp2(G*C - C), C = 10*log2(e).
    const float C10 = 14.42695040888963f;
    float rs[16] = {};
    float cs[2]  = {0.f, 0.f};
    #pragma unroll
    for (int ni = 0; ni < 2; ++ni) {
        const int gcol = colBase + ni * 32 + l31;
        #pragma unroll
        for (int r = 0; r < 16; ++r) {
            const int lrow = (r & 3) + 8 * (r >> 2) + 4 * h0;
            const int grow = rowBase + wave * 32 + lrow;
            float e = __builtin_amdgcn_exp2f(fmaf(acc[ni][r], C10, -C10));
            if (inDiag && grow == gcol) e = 0.f;   // exclude diagonal exactly
            rs[r] += e;
            cs[ni] += e;
            // targets: rows 0/1 of G give 10*G[t, j0] transposed.
            // Only bx==0, wave 0, h0==0, r<2 hits; disjoint cols -> store.
            if (rowBase == 0 && wave == 0 && grow < 2) {
                const int j0 = ((gcol & (BB - 1)) == 0) ? 1 : 0;
                if (grow == j0) targets[gcol] = 10.f * acc[ni][r];
            }
        }
    }
    // Row sums -> slice cy (unique writer per (cy,row)): butterfly over the
    // 32 col-lanes (h0 halves hold different rows), l31==0 stores.
    #pragma unroll
    for (int m = 1; m <= 16; m <<= 1)
        #pragma unroll
        for (int r = 0; r < 16; ++r)
            rs[r] += __shfl_xor(rs[r], m);
    if (l31 == 0) {
        #pragma unroll
        for (int r = 0; r < 16; ++r)
            rpart[(size_t)cy * NN + rowBase + wave * 32
                  + (r & 3) + 8 * (r >> 2) + 4 * h0] = rs[r];
    }
    // Col sums -> slice 128+bx (unique writer per (bx, col)): combine h0
    // halves, fold 4 waves via 1 KB LDS overlay on Bs, coalesced store.
    if (!inDiag) {
        cs[0] += __shfl_xor(cs[0], 32);
        cs[1] += __shfl_xor(cs[1], 32);
        float* cpart = (float*)Bs;              // [4][64] overlay
        __syncthreads();                        // all Bs MFMA reads complete
        if (h0 == 0) {
            cpart[wave * TN + l31]      = cs[0];
            cpart[wave * TN + 32 + l31] = cs[1];
        }
        __syncthreads();
        if (tid < TN) {
            float v = cpart[tid] + cpart[TN + tid]
                    + cpart[2 * TN + tid] + cpart[3 * TN + tid];
            rpart[(size_t)(128 + bx) * NN + colBase + tid] = v;
        }
    }
}

// ---------------- kernel 3: fold valid slices per row + loss term ----------
// 32 blocks x 256 threads, one row each. NO zeroing needed: exact bounds.
// Row-path slices cy >= 2*(i>>7); col-path slices bx <= ((i>>6)-2)/2
// (covers j < 128*(i>>7) exactly; row-path covers j >= 128*(i>>7)).
__global__ __launch_bounds__(256)
void reduce_kernel(const float* __restrict__ rpart,
                   const float* __restrict__ targets, float* __restrict__ wacc) {
    const int i = blockIdx.x * 256 + threadIdx.x;
    float s = 0.f;
    const int sl0 = 2 * (i >> 7);
    #pragma unroll 4
    for (int sl = sl0; sl < 128; ++sl)
        s += rpart[(size_t)sl * NN + i];
    const int c = i >> 6;
    if (c >= 2) {
        const int bxmax = (c - 2) >> 1;
        #pragma unroll 4
        for (int bx = 0; bx <= bxmax; ++bx)
            s += rpart[(size_t)(128 + bx) * NN + i];
    }
    float term = targets[i] - 10.f - __logf(s);
    #pragma unroll
    for (int off = 1; off <= 32; off <<= 1) term += __shfl_xor(term, off);
    __shared__ float red[4];
    if ((threadIdx.x & 63) == 0) red[threadIdx.x >> 6] = term;
    __syncthreads();
    if (threadIdx.x == 0)
        atomicAdd(wacc, red[0] + red[1] + red[2] + red[3]);
}

// ---------------- kernel 4: write scalar output ----------------------------
__global__ void write_kernel(const float* __restrict__ wacc,
                             float* __restrict__ out) {
    out[0] = -wacc[0] / (float)NN;
}

extern "C" void kernel_launch(void* const* d_in, const int* in_sizes, int n_in,
                              void* d_out, int out_size, void* d_ws, size_t ws_size,
                              hipStream_t stream) {
    const float* zi = (const float*)d_in[0];
    const float* zj = (const float*)d_in[1];

    unsigned char* M = (unsigned char*)d_ws;                          // 4 MB fp8
    float* rpart   = (float*)((char*)d_ws + (size_t)NN * DD);         // 6 MB
    float* targets = rpart + (size_t)NSLICE * NN;                     // 32 KB
    float* wacc    = targets + NN;                                    // 4 B
    float* out = (float*)d_out;

    normalize_kernel<<<NN / 4, 256, 0, stream>>>(zi, zj, M, wacc);
    gram_lse_kernel<<<NBLK, 256, 0, stream>>>(M, rpart, targets);
    reduce_kernel<<<NN / 256, 256, 0, stream>>>(rpart, targets, wacc);
    write_kernel<<<1, 1, 0, stream>>>(wacc, out);
}

// Round 8
// 114.859 us; speedup vs baseline: 1.1262x; 1.0557x over previous
//
#include <hip/hip_runtime.h>
#include <hip/hip_bf16.h>
#include <hip/hip_fp8.h>

// SimCLR NT-Xent loss on MI355X.
// loss = -(1/2B) sum_t [ 10*G[t,j0(t)] - (10 + log sum_{j!=t} exp(10*G[t,j]-10)) ]
// where G = M M^T, M = l2norm rows of [z_i; z_j], j0 = (t%B==0) ? 1 : 0.
// Round 13: T4 counted-vmcnt pipeline on the empirically-best structure.
// R1-R7 ledger: every variant either drained vmcnt(0) per chunk (R1-R3)
// or put waited-on global gathers in the wave's critical path (R4-R7);
// all landed 41-55 us with every pipe <30%. The catalog's m218 result:
// 8-phase with drain-to-0 == 1-phase; COUNTED vmcnt is the +38-73% lever.
// This round: R2's verified 128x128 fp8 16x16x32 structure + TRIPLE
// buffer (3x16 KB LDS) + s_waitcnt vmcnt(4) (never 0 until last chunk) +
// raw s_barrier. Chunk t+1's 4 gload_lds stay in flight across every
// barrier; stage(t+2) issues right after the barrier (slot (t+2)%3 ==
// (t-1)%3 is safe: all waves past barrier => done reading chunk t-1).
// Epilogue: collision-free rpart slices (no atomics, no zeroing; reducer
// uses exact-cover bounds).

#define BB 4096      // batch B
#define DD 512       // feature dim (bytes per row in fp8)
#define NN 8192      // 2B rows of G
#define TILE 128     // block tile (rows x cols)
#define KB 64        // K bytes (=elements) staged per LDS chunk
#define NBLK 2080    // 64*65/2 upper-triangle block tiles
#define NSLICE 256   // 128 row-path (2*by+wcolhalf) + 128 col-path (2*bx+wrowhalf)

typedef __attribute__((ext_vector_type(4))) float f32x4;

#define AS1 __attribute__((address_space(1)))
#define AS3 __attribute__((address_space(3)))
static __device__ __forceinline__ void gload_lds16(const void* g, void* l) {
    __builtin_amdgcn_global_load_lds((const AS1 void*)g, (AS3 void*)l, 16, 0, 0);
}

// ---------------- kernel 1: L2-normalize rows -> fp8; zero wacc ------------
__global__ __launch_bounds__(256)
void normalize_kernel(const float* __restrict__ zi, const float* __restrict__ zj,
                      unsigned char* __restrict__ M, float* __restrict__ wacc) {
    if (blockIdx.x == 0 && threadIdx.x == 0) wacc[0] = 0.f;
    const int wave = threadIdx.x >> 6;
    const int lane = threadIdx.x & 63;
    const int row  = blockIdx.x * 4 + wave;      // 2048 blocks * 4 rows
    const float* src = (row < BB) ? (zi + (size_t)row * DD)
                                  : (zj + (size_t)(row - BB) * DD);
    float4 v0 = ((const float4*)src)[lane * 2 + 0];
    float4 v1 = ((const float4*)src)[lane * 2 + 1];
    float ss = v0.x*v0.x + v0.y*v0.y + v0.z*v0.z + v0.w*v0.w
             + v1.x*v1.x + v1.y*v1.y + v1.z*v1.z + v1.w*v1.w;
    #pragma unroll
    for (int off = 1; off <= 32; off <<= 1) ss += __shfl_xor(ss, off);
    const float inv = rsqrtf(ss);
    const float vals[8] = {v0.x*inv, v0.y*inv, v0.z*inv, v0.w*inv,
                           v1.x*inv, v1.y*inv, v1.z*inv, v1.w*inv};
    union { long u; unsigned char b[8]; } pk;
    #pragma unroll
    for (int j = 0; j < 8; ++j)
        pk.b[j] = __hip_cvt_float_to_fp8(vals[j], __HIP_SATFINITE, __HIP_E4M3);
    ((long*)(M + (size_t)row * DD))[lane] = pk.u;
}

// ---------------- kernel 2: Gram tile + exp partial sums -------------------
// 2080 blocks, one upper-triangle 128x128 tile each (by >= bx).
// Wave w: rows wr=(w>>1)*64, cols wc=(w&1)*64; acc[4][4] of 16x16 fp8 MFMA
// (R2's verified core: swizzle, fragment reads, C/D map all unchanged).
__global__ __launch_bounds__(256, 3)
void gram_lse_kernel(const unsigned char* __restrict__ Mg,
                     float* __restrict__ rpart, float* __restrict__ targets) {
    __shared__ __align__(16) char As[3][TILE * KB];   // 3 x 8 KB
    __shared__ __align__(16) char Bs[3][TILE * KB];   // 3 x 8 KB

    // XCD-banded order: dispatch d -> band d%8 (one XCD), 260 tiles per band.
    const int d = blockIdx.x;
    const int p = (d & 7) * 260 + (d >> 3);
    int by = (int)((sqrtf(8.0f * (float)p + 1.0f) - 1.0f) * 0.5f);
    while ((by + 1) * (by + 2) / 2 <= p) ++by;
    while (by * (by + 1) / 2 > p) --by;
    const int bx = p - by * (by + 1) / 2;

    const int rowBase = bx * TILE;
    const int colBase = by * TILE;
    const bool diag = (bx == by);
    const int tid  = threadIdx.x;
    const int wave = tid >> 6;
    const int lane = tid & 63;
    const int wr = (wave >> 1) * 64;
    const int wc = (wave & 1) * 64;
    const int l15 = lane & 15;
    const int l4  = lane >> 4;          // quad 0..3

    // staging gather (R2-verified): dest granule q = issue*256+tid ->
    // row = q>>2, pos = tid&3, source granule sg = pos ^ ((row>>1)&3).
    const int sg  = (tid & 3) ^ ((tid >> 3) & 3);
    const int sr0 = tid >> 2;
    const unsigned char* gA0 = Mg + (size_t)(rowBase + sr0) * DD + sg * 16;
    const unsigned char* gB0 = Mg + (size_t)(colBase + sr0) * DD + sg * 16;

    // fragment read pattern (R2-verified)
    const int r2 = (l15 >> 1) & 3;
    const int qh = l4 >> 1, ql = l4 & 1;
    const int aoff0 = (wr + l15) * KB + ql * 8;
    const int boff0 = (wc + l15) * KB + ql * 8;

    f32x4 acc[4][4] = {};

    // Stage chunk c into slot c%3: 4 gload_lds per thread (A x2, B x2).
    // B staged even on diag tiles (uniform vmcnt literals; 64 redundant
    // 8KB stages out of 2080 blocks is noise).
#define STAGE(c) do {                                                   \
        const int k0_ = (c) * KB;                                       \
        char* lA_ = As[(c) % 3] + tid * 16;                             \
        char* lB_ = Bs[(c) % 3] + tid * 16;                             \
        gload_lds16(gA0 + k0_,           lA_);                          \
        gload_lds16(gA0 + k0_ + 64 * DD, lA_ + 4096);                   \
        gload_lds16(gB0 + k0_,           lB_);                          \
        gload_lds16(gB0 + k0_ + 64 * DD, lB_ + 4096);                   \
    } while (0)

    STAGE(0);
    STAGE(1);

    // ---- counted-vmcnt main loop: vmcnt(4) keeps chunk t+1 in flight ----
    #pragma unroll
    for (int t = 0; t < 8; ++t) {
        if (t < 7) asm volatile("s_waitcnt vmcnt(4)" ::: "memory");
        else       asm volatile("s_waitcnt vmcnt(0)" ::: "memory");
        __builtin_amdgcn_s_barrier();          // chunk t resident, everyone
        __builtin_amdgcn_sched_barrier(0);     // done reading chunk t-1
        if (t + 2 < 8) STAGE(t + 2);           // overwrites slot (t-1)%3: safe
        const char* Asrc = As[t % 3];
        const char* Bsrc = Bs[t % 3];
        #pragma unroll
        for (int ks = 0; ks < 2; ++ks) {
            const int so = ((((ks << 1) | qh) ^ r2) << 4);
            long a[4], b[4];
            #pragma unroll
            for (int mi = 0; mi < 4; ++mi)
                a[mi] = *(const long*)(Asrc + aoff0 + mi * 1024 + so);
            #pragma unroll
            for (int ni = 0; ni < 4; ++ni)
                b[ni] = *(const long*)(Bsrc + boff0 + ni * 1024 + so);
            #pragma unroll
            for (int mi = 0; mi < 4; ++mi)
                #pragma unroll
                for (int ni = 0; ni < 4; ++ni)
                    acc[mi][ni] = __builtin_amdgcn_mfma_f32_16x16x32_fp8_fp8(
                        a[mi], b[ni], acc[mi][ni], 0, 0, 0);
        }
    }
#undef STAGE

    // ---- epilogue ----
    // C/D layout: col = lane&15, row = (lane>>4)*4 + reg.
    // e = exp(10*G - 10) = exp2(G*C - C), C = 10*log2(e).
    const float C10 = 14.42695040888963f;
    float cs[4] = {0.f, 0.f, 0.f, 0.f};
    #pragma unroll
    for (int mi = 0; mi < 4; ++mi) {
        float rs[4] = {0.f, 0.f, 0.f, 0.f};
        #pragma unroll
        for (int ni = 0; ni < 4; ++ni) {
            const int gcol = colBase + wc + ni * 16 + l15;
            #pragma unroll
            for (int r = 0; r < 4; ++r) {
                const int grow = rowBase + wr + mi * 16 + l4 * 4 + r;
                float e = __builtin_amdgcn_exp2f(fmaf(acc[mi][ni][r], C10, -C10));
                if (diag && grow == gcol) e = 0.f;   // exclude diagonal exactly
                rs[r] += e;
                cs[ni] += e;
                // targets: rows 0/1 of G give 10*G[t, j0] transposed.
                if (rowBase == 0 && grow < 2) {
                    const int j0 = ((gcol & (BB - 1)) == 0) ? 1 : 0;
                    if (grow == j0) targets[gcol] = 10.f * acc[mi][ni][r];
                }
            }
        }
        // reduce across the 16 col-lanes; l15==0 stores 4 rows per (mi,l4)
        #pragma unroll
        for (int m = 1; m <= 8; m <<= 1)
            #pragma unroll
            for (int r = 0; r < 4; ++r)
                rs[r] += __shfl_xor(rs[r], m);
        if (l15 == 0) {
            // row-path slice 2*by + (wave&1): unique writer per (slice,row)
            #pragma unroll
            for (int r = 0; r < 4; ++r)
                rpart[(size_t)(2 * by + (wave & 1)) * NN
                      + rowBase + wr + mi * 16 + l4 * 4 + r] = rs[r];
        }
    }
    if (!diag) {
        // col sums: reduce over the 4 row-quads (bits 4,5), l4==0 stores.
        #pragma unroll
        for (int ni = 0; ni < 4; ++ni) {
            cs[ni] += __shfl_xor(cs[ni], 16);
            cs[ni] += __shfl_xor(cs[ni], 32);
        }
        if (l4 == 0) {
            // col-path slice 128 + 2*bx + (wave>>1): unique writer
            #pragma unroll
            for (int ni = 0; ni < 4; ++ni)
                rpart[(size_t)(128 + 2 * bx + (wave >> 1)) * NN
                      + colBase + wc + ni * 16 + l15] = cs[ni];
        }
    }
}

// ---------------- kernel 3: fold valid slices per row + loss term ----------
// 32 blocks x 256 threads, one row each. Exact-cover bounds, no zeroing:
// row i (panel pi=i>>7): row-path slices [2*pi, 128); col-path slices
// [128, 128+2*pi). Both contiguous, coalesced reads.
__global__ __launch_bounds__(256)
void reduce_kernel(const float* __restrict__ rpart,
                   const float* __restrict__ targets, float* __restrict__ wacc) {
    const int i = blockIdx.x * 256 + threadIdx.x;
    const int pi = i >> 7;
    float s = 0.f;
    #pragma unroll 4
    for (int sl = 2 * pi; sl < 128; ++sl)
        s += rpart[(size_t)sl * NN + i];
    #pragma unroll 4
    for (int sl = 128; sl < 128 + 2 * pi; ++sl)
        s += rpart[(size_t)sl * NN + i];
    float term = targets[i] - 10.f - __logf(s);
    #pragma unroll
    for (int off = 1; off <= 32; off <<= 1) term += __shfl_xor(term, off);
    __shared__ float red[4];
    if ((threadIdx.x & 63) == 0) red[threadIdx.x >> 6] = term;
    __syncthreads();
    if (threadIdx.x == 0)
        atomicAdd(wacc, red[0] + red[1] + red[2] + red[3]);
}

// ---------------- kernel 4: write scalar output ----------------------------
__global__ void write_kernel(const float* __restrict__ wacc,
                             float* __restrict__ out) {
    out[0] = -wacc[0] / (float)NN;
}

extern "C" void kernel_launch(void* const* d_in, const int* in_sizes, int n_in,
                              void* d_out, int out_size, void* d_ws, size_t ws_size,
                              hipStream_t stream) {
    const float* zi = (const float*)d_in[0];
    const float* zj = (const float*)d_in[1];

    unsigned char* M = (unsigned char*)d_ws;                          // 4 MB fp8
    float* rpart   = (float*)((char*)d_ws + (size_t)NN * DD);         // 8 MB
    float* targets = rpart + (size_t)NSLICE * NN;                     // 32 KB
    float* wacc    = targets + NN;                                    // 4 B
    float* out = (float*)d_out;

    normalize_kernel<<<NN / 4, 256, 0, stream>>>(zi, zj, M, wacc);
    gram_lse_kernel<<<NBLK, 256, 0, stream>>>(M, rpart, targets);
    reduce_kernel<<<NN / 256, 256, 0, stream>>>(rpart, targets, wacc);
    write_kernel<<<1, 1, 0, stream>>>(wacc, out);
}